// Round 4
// baseline (353.202 us; speedup 1.0000x reference)
//
#include <hip/hip_runtime.h>
#include <hip/hip_bf16.h>

// MinGRU: L=2 layers of  h_t = (1-z_t) h_{t-1} + z_t g(pre_t)
// R4: cv flipped to time-major [(b*H+h)*S + t] -> GEMM epilogue does 16B packed
// stores (4 consecutive t per lane); scan_emit streams contiguous reads with
// 2 h-chains/thread and fully-coalesced writes.

#define L_ 2
#define B_ 8
#define S_ 2048
#define D_ 1024
#define H_ 1024
#define M_ (B_*S_)     // 16384
#define NC 32          // chunks per sequence
#define CL (S_/NC)     // 64 steps per chunk (GEMM m-tile 128 = 2 chunks)

typedef __bf16    bf16x8 __attribute__((ext_vector_type(8)));
typedef float     f32x4  __attribute__((ext_vector_type(4)));
typedef _Float16  h2     __attribute__((ext_vector_type(2)));

__device__ __forceinline__ ushort f2bf(float f) {
    union { __hip_bfloat16 h; ushort u; } c;
    c.h = __float2bfloat16(f);   // RNE
    return c.u;
}

__device__ __forceinline__ void async16(const void* g, void* l) {
    __builtin_amdgcn_global_load_lds(
        (const __attribute__((address_space(1))) unsigned int*)g,
        (__attribute__((address_space(3))) unsigned int*)l, 16, 0, 0);
}

__global__ __launch_bounds__(256) void cast_f32_bf16(const float* __restrict__ in,
                                                     ushort* __restrict__ out, int n4) {
    int i = blockIdx.x * 256 + threadIdx.x;
    if (i >= n4) return;
    float4 v = ((const float4*)in)[i];
    ushort4 o;
    o.x = f2bf(v.x); o.y = f2bf(v.y); o.z = f2bf(v.z); o.w = f2bf(v.w);
    ((ushort4*)out)[i] = o;
}

// LDS layout: row R (64 ushorts = 8 chunks of 16B); logical chunk c stored at
// physical chunk c ^ (R&7).  Offset in ushorts:
#define SWZ(R, c) (((R) << 6) + ((((c) ^ ((R) & 7))) << 3))

// Fused: k = A@Wz^T+bz, pre = A@Wh^T+bh ; cv = (sigmoid(-k), sigmoid(k)*g(pre)) fp16x2,
// cv layout TIME-MAJOR: cv[(b*H + h)*S + t].
// Tile 128m x 64n = 2 chunks of CL=64; epilogue composes both chunk affines -> Ac, Bc.
__global__ __launch_bounds__(256) void gemm_fused(const ushort* __restrict__ A,
                                                  const ushort* __restrict__ Wz,
                                                  const ushort* __restrict__ Wh,
                                                  const float* __restrict__ bz,
                                                  const float* __restrict__ bh,
                                                  h2* __restrict__ cv,
                                                  float* __restrict__ Ac,
                                                  float* __restrict__ Bc)
{
    __shared__ __align__(16) ushort sm[16384];       // 32 KiB
    ushort* As = sm;            // 128 x 64
    ushort* Zs = sm + 8192;     //  64 x 64
    ushort* Hs = sm + 12288;    //  64 x 64

    const int t    = threadIdx.x;
    const int lane = t & 63;
    const int wave = t >> 6;
    // XCD-aware swizzle: the 16 blocks sharing an A-tile (same mblk) get the same
    // blockIdx%8 -> same XCD L2.
    const int xcd = (int)blockIdx.x & 7;
    const int k8  = (int)blockIdx.x >> 3;            // 0..255
    const int nblk = k8 & 15;
    const int mblk = ((k8 >> 4) << 3) + xcd;         // 0..127
    const int m0 = mblk * 128;
    const int n0 = nblk * 64;
    const int wm = (wave >> 1) * 64;                 // 0 / 64
    const int wn = (wave & 1) * 32;                  // 0 / 32

    const int srow   = lane >> 3;                    // 0..7
    const int scol_g = (((lane & 7) ^ srow) << 3);   // swizzled source chunk

    f32x4 accz[4][2] = {};
    f32x4 acch[4][2] = {};
    const int lrow = lane & 15;
    const int lcq  = lane >> 4;                      // chunk sub-index 0..3

    for (int kb = 0; kb < D_; kb += 64) {
        __syncthreads();
        #pragma unroll
        for (int i = 0; i < 4; ++i) {                // A: 128 rows
            int r = i*32 + wave*8;
            async16(&A[(size_t)(m0 + r + srow)*D_ + kb + scol_g], &As[r*64]);
        }
        #pragma unroll
        for (int i = 0; i < 2; ++i) {                // Wz, Wh: 64 rows each
            int r = i*32 + wave*8;
            async16(&Wz[(size_t)(n0 + r + srow)*D_ + kb + scol_g], &Zs[r*64]);
            async16(&Wh[(size_t)(n0 + r + srow)*D_ + kb + scol_g], &Hs[r*64]);
        }
        __syncthreads();                             // drains vmcnt -> LDS valid
        #pragma unroll
        for (int kk = 0; kk < 64; kk += 32) {
            const int cq = (kk >> 3) + lcq;          // logical chunk 0..7
            bf16x8 af[4];
            #pragma unroll
            for (int mt = 0; mt < 4; ++mt) {
                int R = wm + mt*16 + lrow;
                uint4 u = *(const uint4*)&As[SWZ(R, cq)];
                af[mt] = __builtin_bit_cast(bf16x8, u);
            }
            #pragma unroll
            for (int nt = 0; nt < 2; ++nt) {
                int R = wn + nt*16 + lrow;
                uint4 uz = *(const uint4*)&Zs[SWZ(R, cq)];
                uint4 uh = *(const uint4*)&Hs[SWZ(R, cq)];
                bf16x8 zb = __builtin_bit_cast(bf16x8, uz);
                bf16x8 hb = __builtin_bit_cast(bf16x8, uh);
                #pragma unroll
                for (int mt = 0; mt < 4; ++mt) {
                    accz[mt][nt] = __builtin_amdgcn_mfma_f32_16x16x32_bf16(af[mt], zb, accz[mt][nt], 0, 0, 0);
                    acch[mt][nt] = __builtin_amdgcn_mfma_f32_16x16x32_bf16(af[mt], hb, acch[mt][nt], 0, 0, 0);
                }
            }
        }
    }

    __syncthreads();                                 // MFMA LDS reads done; reuse LDS
    float2* seg = (float2*)sm;                       // [32 segs][stride 65] float2

    // C/D layout [m89-verified]: col = lane&15, row = (lane>>4)*4 + reg
    const int colq = lane & 15;
    const int rowq = (lane >> 4) * 4;
    const int bq   = m0 >> 11;                       // batch (S=2048)
    const int tb   = m0 & (S_-1);                    // tile's base timestep
    #pragma unroll
    for (int nt = 0; nt < 2; ++nt) {
        const int n = n0 + wn + nt*16 + colq;        // h index
        const float bzv = bz[n];
        const float bhv = bh[n];
        #pragma unroll
        for (int mt = 0; mt < 4; ++mt) {
            float a = 1.f, bb = 0.f;                 // affine over 4 consecutive t
            union { h2 h[4]; uint4 u; } pk;
            #pragma unroll
            for (int r = 0; r < 4; ++r) {
                float k = accz[mt][nt][r] + bzv;
                float p = acch[mt][nt][r] + bhv;
                float e   = __expf(-fabsf(k));
                float inv = 1.0f / (1.0f + e);
                float z   = (k >= 0.f) ? inv     : e * inv;
                float c   = (k >= 0.f) ? e * inv : inv;
                float g;
                if (p >= 0.f) g = p + 0.5f;
                else { float eg = __expf(p); g = eg / (1.0f + eg); }
                float v = z * g;
                pk.h[r][0] = (_Float16)c; pk.h[r][1] = (_Float16)v;
                bb = fmaf(c, bb, v);
                a *= c;
            }
            const int tt = tb + wm + mt*16 + rowq;   // 16B-aligned (mult of 4)
            *(uint4*)&cv[(size_t)(bq*H_ + n)*S_ + tt] = pk.u;
            const int sidx = (wm >> 2) + mt*4 + (rowq >> 2);   // 0..31, time-ordered
            seg[sidx*65 + wn + nt*16 + colq] = make_float2(a, bb);
        }
    }
    __syncthreads();
    // two chunks of CL=64 per tile: segs 0..15 -> chunk 2*c0, segs 16..31 -> 2*c0+1
    if (t < 128) {
        const int col  = t & 63;
        const int half = t >> 6;
        float a = 1.f, bb = 0.f;
        #pragma unroll
        for (int s = 0; s < 16; ++s) {
            float2 e = seg[(half*16 + s)*65 + col];
            bb = fmaf(e.x, bb, e.y);
            a *= e.x;
        }
        const int chunk = ((m0 >> 6) & (NC - 1)) + half;
        const int q = (bq*NC + chunk)*H_ + n0 + col;
        Ac[q] = a; Bc[q] = bb;
    }
}

// Scan over the NC chunk-affines per (b,h); emit incoming h per chunk.
__global__ __launch_bounds__(256) void scan_chunk_combine(const float* __restrict__ Ac,
                                                          const float* __restrict__ Bc,
                                                          float* __restrict__ hin)
{
    int q = blockIdx.x * 256 + threadIdx.x;          // 0 .. B*H-1
    int h = q & (H_-1);
    int b = q >> 10;
    float hcur = 0.5f;                               // h0 = g(0) = 0.5
    #pragma unroll
    for (int c = 0; c < NC; ++c) {
        int idx = (b*NC + c)*H_ + h;
        hin[idx] = hcur;
        hcur = fmaf(Ac[idx], hcur, Bc[idx]);
    }
}

// Re-scan each chunk with known incoming h. Time-major cv: each thread streams
// two contiguous 256B runs (h, h+1); writes are coalesced across lanes (fixed t).
__global__ __launch_bounds__(256) void scan_emit(const h2* __restrict__ cv,
                                                 const float* __restrict__ hin,
                                                 float* __restrict__ outf,
                                                 ushort* __restrict__ outb,
                                                 const int write_bf16)
{
    int q = blockIdx.x * 256 + threadIdx.x;          // 0 .. B*NC*H/2-1
    int hp = (q & 511) * 2;                          // h, h+1
    int c  = (q >> 9) & (NC-1);
    int b  = q >> 14;
    const h2* p0 = cv + (size_t)(b*H_ + hp    )*S_ + c*CL;
    const h2* p1 = cv + (size_t)(b*H_ + hp + 1)*S_ + c*CL;
    float2 hv = *(const float2*)&hin[(b*NC + c)*H_ + hp];
    float h0 = hv.x, h1 = hv.y;
    const size_t obase = (size_t)(b*S_ + c*CL)*H_ + hp;
    if (write_bf16) {
        #pragma unroll 4
        for (int i = 0; i < CL/4; ++i) {
            union { uint4 u; h2 h[4]; } e0, e1;
            e0.u = *(const uint4*)&p0[i*4];
            e1.u = *(const uint4*)&p1[i*4];
            #pragma unroll
            for (int j = 0; j < 4; ++j) {
                h0 = fmaf((float)e0.h[j][0], h0, (float)e0.h[j][1]);
                h1 = fmaf((float)e1.h[j][0], h1, (float)e1.h[j][1]);
                ushort2 o; o.x = f2bf(h0); o.y = f2bf(h1);
                *(ushort2*)&outb[obase + (size_t)(i*4 + j)*H_] = o;
            }
        }
    } else {
        #pragma unroll 4
        for (int i = 0; i < CL/4; ++i) {
            union { uint4 u; h2 h[4]; } e0, e1;
            e0.u = *(const uint4*)&p0[i*4];
            e1.u = *(const uint4*)&p1[i*4];
            #pragma unroll
            for (int j = 0; j < 4; ++j) {
                h0 = fmaf((float)e0.h[j][0], h0, (float)e0.h[j][1]);
                h1 = fmaf((float)e1.h[j][0], h1, (float)e1.h[j][1]);
                *(float2*)&outf[obase + (size_t)(i*4 + j)*H_] = make_float2(h0, h1);
            }
        }
    }
}

extern "C" void kernel_launch(void* const* d_in, const int* in_sizes, int n_in,
                              void* d_out, int out_size, void* d_ws, size_t ws_size,
                              hipStream_t stream)
{
    const float* x  = (const float*)d_in[0];
    const float* Wz = (const float*)d_in[1];
    const float* bz = (const float*)d_in[2];
    const float* Wh = (const float*)d_in[3];
    const float* bh = (const float*)d_in[4];
    float* out = (float*)d_out;

    // workspace (~107 MiB)
    ushort* xb  = (ushort*)d_ws;                      // M*D bf16        (32 MiB)
    ushort* wzb = xb  + (size_t)M_*D_;                // L*H*D bf16      (4 MiB)
    ushort* whb = wzb + (size_t)L_*H_*D_;             // L*H*D bf16      (4 MiB)
    h2*     cv  = (h2*)(whb + (size_t)L_*H_*D_);      // M*H fp16x2      (64 MiB)
    float*  Ac  = (float*)(cv + (size_t)M_*H_);       // B*NC*H          (1 MiB)
    float*  Bc  = Ac + B_*NC*H_;
    float*  hin = Bc + B_*NC*H_;

    cast_f32_bf16<<<(M_*D_/4)/256, 256, 0, stream>>>(x, xb, M_*D_/4);
    cast_f32_bf16<<<(L_*H_*D_/4)/256, 256, 0, stream>>>(Wz, wzb, L_*H_*D_/4);
    cast_f32_bf16<<<(L_*H_*D_/4)/256, 256, 0, stream>>>(Wh, whb, L_*H_*D_/4);

    const int gemm_grid = (M_/128) * (H_/64);        // 2048 blocks
    for (int l = 0; l < L_; ++l) {
        gemm_fused<<<gemm_grid, 256, 0, stream>>>(xb,
                                                  wzb + (size_t)l*H_*D_,
                                                  whb + (size_t)l*H_*D_,
                                                  bz + l*H_, bh + l*H_,
                                                  cv, Ac, Bc);
        scan_chunk_combine<<<(B_*H_)/256, 256, 0, stream>>>(Ac, Bc, hin);
        scan_emit<<<(B_*NC*H_/2)/256, 256, 0, stream>>>(cv, hin, out, xb, (l == 0) ? 1 : 0);
    }
}